// Round 4
// baseline (600.656 us; speedup 1.0000x reference)
//
#include <hip/hip_runtime.h>
#include <math.h>

#define EPSF 1e-9f
#define KK 128
#define NPK 128   // N - K
#define MTOP 10   // m

// Broadcast a float4 held distributed across a 32-lane half-wave.
__device__ __forceinline__ float4 shfl4(float4 v, int srcLane) {
    float4 r;
    r.x = __shfl(v.x, srcLane, 32);
    r.y = __shfl(v.y, srcLane, 32);
    r.z = __shfl(v.z, srcLane, 32);
    r.w = __shfl(v.w, srcLane, 32);
    return r;
}

__device__ __forceinline__ float max8(const float v[8]) {
    float a = fmaxf(v[0], v[1]), b = fmaxf(v[2], v[3]);
    float c = fmaxf(v[4], v[5]), d = fmaxf(v[6], v[7]);
    return fmaxf(fmaxf(a, b), fmaxf(c, d));
}

// Consume one 8-row P buffer: acc[r] += S[row][k0+kk] * P[k0+kk][j4..j4+3].
// Sample scalars come from vs[] via width-32 shuffles (lane sl holds
// S[row][4*sl..4*sl+3]) -- no VMEM traffic in the inner loop except P.
__device__ __forceinline__ void compute8(float4 (&acc)[5], const float4 (&buf)[8],
                                         const float4 (&vs)[5], int k0) {
    const int sl = k0 >> 2;
    #pragma unroll
    for (int r = 0; r < 5; ++r) {
        float4 s0 = shfl4(vs[r], sl);
        float4 s1 = shfl4(vs[r], sl + 1);
        #pragma unroll
        for (int kk = 0; kk < 4; ++kk) {
            float sa = (kk == 0) ? s0.x : (kk == 1) ? s0.y : (kk == 2) ? s0.z : s0.w;
            acc[r].x = fmaf(sa, buf[kk].x, acc[r].x);
            acc[r].y = fmaf(sa, buf[kk].y, acc[r].y);
            acc[r].z = fmaf(sa, buf[kk].z, acc[r].z);
            acc[r].w = fmaf(sa, buf[kk].w, acc[r].w);
            float sb = (kk == 0) ? s1.x : (kk == 1) ? s1.y : (kk == 2) ? s1.z : s1.w;
            acc[r].x = fmaf(sb, buf[4 + kk].x, acc[r].x);
            acc[r].y = fmaf(sb, buf[4 + kk].y, acc[r].y);
            acc[r].z = fmaf(sb, buf[4 + kk].z, acc[r].z);
            acc[r].w = fmaf(sb, buf[4 + kk].w, acc[r].w);
        }
    }
}

// One 128-thread block (2 waves) per batch element b.
// Half-wave hw = wave*2 + sg owns rows r0 = 5*hw .. r0+5 (4 half-waves x 5 = 20).
// Within a half-wave, lane jg = lane&31 owns columns [4jg, 4jg+4).
//
// R1/R2 lesson: all register arrays indexed with compile-time constants only.
// R3 lesson: kernel was latency-bound (1000 cyc/load serialized, 2 waves/SIMD)
// -> this version doubles TLP (4 waves/SIMD) and pipelines P loads through
// explicit ping-pong 8-row register buffers; sample values come from shuffles.
__global__ __launch_bounds__(128, 4) void fused_kernel(
    const float* __restrict__ y_pred, const float* __restrict__ y_true,
    const float* __restrict__ P, const float* __restrict__ samples,
    float* __restrict__ accum /* [0]=logmse_sum, [1]=penalty_sum */)
{
    const int tid  = threadIdx.x;
    const int wave = tid >> 6;
    const int lane = tid & 63;
    const int sg   = lane >> 5;
    const int hw   = (wave << 1) | sg;   // 0..3
    const int jg   = lane & 31;
    const int j4   = jg << 2;
    const int r0   = hw * 5;
    const int b    = blockIdx.x;

    const float* __restrict__ Pb = P + ((size_t)b << 14);            // b*128*128
    const float* __restrict__ Sb = samples + (size_t)b * (20 * KK);  // b*20*128

    // Persistent sample slices: vs[r] = S[r0+r][j4..j4+3].
    // Used as (a) shuffle source for GEMM scalars, (b) identity part in top-k.
    float4 vs[5];
    #pragma unroll
    for (int r = 0; r < 5; ++r)
        vs[r] = *(const float4*)(Sb + (r0 + r) * KK + j4);

    float4 acc[5];
    #pragma unroll
    for (int r = 0; r < 5; ++r) acc[r] = make_float4(0.f, 0.f, 0.f, 0.f);

    // ---- software-pipelined GEMM over k, 8 P-rows per buffer ----
    float4 pA[8], pB[8];
    #pragma unroll
    for (int kk = 0; kk < 8; ++kk)
        pA[kk] = *(const float4*)(Pb + (size_t)kk * NPK + j4);

    #pragma unroll 1
    for (int k0 = 0; k0 < KK; k0 += 16) {
        #pragma unroll
        for (int kk = 0; kk < 8; ++kk)
            pB[kk] = *(const float4*)(Pb + (size_t)(k0 + 8 + kk) * NPK + j4);
        compute8(acc, pA, vs, k0);
        if (k0 + 16 < KK) {
            #pragma unroll
            for (int kk = 0; kk < 8; ++kk)
                pA[kk] = *(const float4*)(Pb + (size_t)(k0 + 16 + kk) * NPK + j4);
        }
        compute8(acc, pB, vs, k0 + 8);
    }

    // ---- Top-11 per row (half-wave: 32 lanes x 8 vals = 256) ----
    const unsigned long long halfmask =
        sg ? 0xFFFFFFFF00000000ull : 0x00000000FFFFFFFFull;
    float hmax = 0.f;

    #pragma unroll   // FULL unroll: constant indices into acc/vs (R1/R2 lesson)
    for (int r = 0; r < 5; ++r) {
        float v[8];
        v[0] = fabsf(acc[r].x); v[1] = fabsf(acc[r].y);
        v[2] = fabsf(acc[r].z); v[3] = fabsf(acc[r].w);
        v[4] = fabsf(vs[r].x);  v[5] = fabsf(vs[r].y);
        v[6] = fabsf(vs[r].z);  v[7] = fabsf(vs[r].w);

        float m1 = 0.f, m11 = 0.f;
        #pragma unroll 1   // rolled ok: v[] indices inside are constant
        for (int it = 0; it <= MTOP; ++it) {
            float lm = max8(v);
            float Mx = lm;
            #pragma unroll
            for (int d = 16; d >= 1; d >>= 1)
                Mx = fmaxf(Mx, __shfl_xor(Mx, d, 32));
            if (it == 0) m1 = Mx;
            if (it == MTOP) { m11 = Mx; break; }
            unsigned long long ball = __ballot(lm == Mx) & halfmask;
            int first = __ffsll(ball) - 1;
            if (lane == first) {
                bool done = false;
                #pragma unroll
                for (int q = 0; q < 8; ++q) {
                    bool hit = (!done) && (v[q] == Mx);
                    v[q] = hit ? -1.f : v[q];
                    done = done || hit;
                }
            }
        }
        hmax = fmaxf(hmax, m1 / (m11 + EPSF));
    }

    // combine half-waves within the wave, then waves via LDS
    hmax = fmaxf(hmax, __shfl_xor(hmax, 32, 64));
    __shared__ float red[2];
    if (lane == 0) red[wave] = hmax;
    __syncthreads();
    if (tid == 0) {
        float hb  = fmaxf(red[0], red[1]);
        float ypv = y_pred[b];
        float yp  = fmaxf(ypv, EPSF);
        float yt  = fmaxf(y_true[b], EPSF);
        float d   = log2f(yt) - log2f(yp);
        atomicAdd(&accum[0], d * d);
        atomicAdd(&accum[1], fmaxf(hb - ypv, 0.f));
    }
}

__global__ void finalize_kernel(const float* __restrict__ accum,
                                float* __restrict__ out, float invB)
{
    if (threadIdx.x == 0) {
        float logmse    = accum[0] * invB;
        float violation = accum[1] * invB;
        out[0] = logmse + 0.5f * violation;
        out[1] = logmse;
        out[2] = violation;
    }
}

extern "C" void kernel_launch(void* const* d_in, const int* in_sizes, int n_in,
                              void* d_out, int out_size, void* d_ws, size_t ws_size,
                              hipStream_t stream) {
    const float* y_pred  = (const float*)d_in[0];
    const float* y_true  = (const float*)d_in[1];
    const float* P       = (const float*)d_in[2];
    const float* samples = (const float*)d_in[3];
    const int B = in_sizes[0];           // y_pred has B elements

    float* accum = (float*)d_ws;
    hipMemsetAsync(accum, 0, 2 * sizeof(float), stream);

    fused_kernel<<<B, 128, 0, stream>>>(y_pred, y_true, P, samples, accum);
    finalize_kernel<<<1, 64, 0, stream>>>(accum, (float*)d_out, 1.0f / (float)B);
}

// Round 5
// 426.206 us; speedup vs baseline: 1.4093x; 1.4093x over previous
//
#include <hip/hip_runtime.h>
#include <math.h>

#define EPSF 1e-9f
#define KK 128
#define MTOP 10   // m

// One 256-thread block (4 waves) per batch element b.
// Wave w owns sample rows r0=5w..5w+4 (4x5 = 20 rows).
// Lane (0..63) owns columns {2*lane, 2*lane+1} -> the wave covers all 128
// computed columns; identity part lives in the same lanes' vs[] slices.
//
// LESSONS (R1-R4):
//  * Register arrays must use compile-time-constant indices ONLY (R2: a
//    runtime acc[i] put the array in scratch -> 41 MB spill traffic).
//  * NEVER pass register arrays by reference to helper functions (R4:
//    `const float4 (&buf)[8]` params blocked SROA -> 983 MB spill traffic,
//    464 us). Everything is inline in the kernel body below.
//  * R3 was latency-bound (2 waves/SIMD, ~1 load in flight): this version
//    runs up to 8 waves/SIMD with 8 pipelined loads per wave.
__global__ __launch_bounds__(256, 4) void fused_kernel(
    const float* __restrict__ y_pred, const float* __restrict__ y_true,
    const float* __restrict__ P, const float* __restrict__ samples,
    float* __restrict__ accum /* [0]=logmse_sum, [1]=penalty_sum */)
{
    const int tid  = threadIdx.x;
    const int wave = tid >> 6;
    const int lane = tid & 63;
    const int b    = blockIdx.x;
    const int r0   = wave * 5;
    const int j2   = lane << 1;

    const float* __restrict__ Pb = P + ((size_t)b << 14);            // b*128*128
    const float* __restrict__ Sb = samples + (size_t)b * (20 * KK);  // b*20*128

    // vs[r] = S[r0+r][j2..j2+1]; lane m holds elements 2m,2m+1 of the row.
    // Used as (a) shuffle source for GEMM scalars, (b) identity part in top-k.
    float2 vs[5];
#pragma unroll
    for (int r = 0; r < 5; ++r)
        vs[r] = *(const float2*)(Sb + (r0 + r) * KK + j2);

    float2 acc[5];
#pragma unroll
    for (int r = 0; r < 5; ++r) acc[r] = make_float2(0.f, 0.f);

    // Double-buffered 8-row P chunks in registers (float2/lane = 512B/wave,
    // fully coalesced; 8 loads in flight while the other buffer computes).
    float2 cb[8], nb[8];
#pragma unroll
    for (int i = 0; i < 8; ++i)
        cb[i] = *(const float2*)(Pb + (size_t)i * KK + j2);
#pragma unroll
    for (int i = 0; i < 8; ++i)
        nb[i] = *(const float2*)(Pb + (size_t)(8 + i) * KK + j2);

#pragma unroll 1
    for (int k0 = 0; k0 < KK; k0 += 16) {
        // ---- compute ks [k0, k0+8) from cb ----
        {
            const int bl = k0 >> 1;
#pragma unroll
            for (int q = 0; q < 4; ++q) {
#pragma unroll
                for (int r = 0; r < 5; ++r) {
                    float sx = __shfl(vs[r].x, bl + q, 64);  // S[r][k0+2q]
                    float sy = __shfl(vs[r].y, bl + q, 64);  // S[r][k0+2q+1]
                    acc[r].x = fmaf(sx, cb[2 * q].x, acc[r].x);
                    acc[r].y = fmaf(sx, cb[2 * q].y, acc[r].y);
                    acc[r].x = fmaf(sy, cb[2 * q + 1].x, acc[r].x);
                    acc[r].y = fmaf(sy, cb[2 * q + 1].y, acc[r].y);
                }
            }
        }
        // refill cb for ks [k0+16, k0+24) while nb computes
        if (k0 + 16 < KK) {
#pragma unroll
            for (int i = 0; i < 8; ++i)
                cb[i] = *(const float2*)(Pb + (size_t)(k0 + 16 + i) * KK + j2);
        }
        // ---- compute ks [k0+8, k0+16) from nb ----
        {
            const int bl = (k0 + 8) >> 1;
#pragma unroll
            for (int q = 0; q < 4; ++q) {
#pragma unroll
                for (int r = 0; r < 5; ++r) {
                    float sx = __shfl(vs[r].x, bl + q, 64);
                    float sy = __shfl(vs[r].y, bl + q, 64);
                    acc[r].x = fmaf(sx, nb[2 * q].x, acc[r].x);
                    acc[r].y = fmaf(sx, nb[2 * q].y, acc[r].y);
                    acc[r].x = fmaf(sy, nb[2 * q + 1].x, acc[r].x);
                    acc[r].y = fmaf(sy, nb[2 * q + 1].y, acc[r].y);
                }
            }
        }
        // refill nb for ks [k0+24, k0+32)
        if (k0 + 16 < KK) {
#pragma unroll
            for (int i = 0; i < 8; ++i)
                nb[i] = *(const float2*)(Pb + (size_t)(k0 + 24 + i) * KK + j2);
        }
    }

    // ---- Top-11 per row across the full wave: 64 lanes x 4 vals = 256 ----
    float hmax = 0.f;
#pragma unroll   // constant indices into acc/vs
    for (int r = 0; r < 5; ++r) {
        float v0 = fabsf(acc[r].x), v1 = fabsf(acc[r].y);
        float v2 = fabsf(vs[r].x),  v3 = fabsf(vs[r].y);
        float m1 = 0.f, m11 = 0.f;
#pragma unroll 1
        for (int it = 0; it <= MTOP; ++it) {
            float lm = fmaxf(fmaxf(v0, v1), fmaxf(v2, v3));
            float Mx = lm;
#pragma unroll
            for (int d = 32; d >= 1; d >>= 1)
                Mx = fmaxf(Mx, __shfl_xor(Mx, d, 64));
            if (it == 0) m1 = Mx;
            if (it == MTOP) { m11 = Mx; break; }
            // remove exactly one instance of Mx (first lane holding it)
            unsigned long long ball = __ballot(lm == Mx);
            int first = __ffsll((unsigned long long)ball) - 1;
            if (lane == first) {
                if (v0 == Mx)      v0 = -1.f;
                else if (v1 == Mx) v1 = -1.f;
                else if (v2 == Mx) v2 = -1.f;
                else               v3 = -1.f;
            }
        }
        hmax = fmaxf(hmax, m1 / (m11 + EPSF));   // wave-uniform
    }

    // ---- combine 4 waves, one atomic pair per block ----
    __shared__ float red[4];
    if (lane == 0) red[wave] = hmax;
    __syncthreads();
    if (tid == 0) {
        float hb  = fmaxf(fmaxf(red[0], red[1]), fmaxf(red[2], red[3]));
        float ypv = y_pred[b];
        float yp  = fmaxf(ypv, EPSF);
        float yt  = fmaxf(y_true[b], EPSF);
        float d   = log2f(yt) - log2f(yp);
        atomicAdd(&accum[0], d * d);
        atomicAdd(&accum[1], fmaxf(hb - ypv, 0.f));
    }
}

__global__ void finalize_kernel(const float* __restrict__ accum,
                                float* __restrict__ out, float invB)
{
    if (threadIdx.x == 0) {
        float logmse    = accum[0] * invB;
        float violation = accum[1] * invB;
        out[0] = logmse + 0.5f * violation;
        out[1] = logmse;
        out[2] = violation;
    }
}

extern "C" void kernel_launch(void* const* d_in, const int* in_sizes, int n_in,
                              void* d_out, int out_size, void* d_ws, size_t ws_size,
                              hipStream_t stream) {
    const float* y_pred  = (const float*)d_in[0];
    const float* y_true  = (const float*)d_in[1];
    const float* P       = (const float*)d_in[2];
    const float* samples = (const float*)d_in[3];
    const int B = in_sizes[0];           // y_pred has B elements

    float* accum = (float*)d_ws;
    hipMemsetAsync(accum, 0, 2 * sizeof(float), stream);

    fused_kernel<<<B, 256, 0, stream>>>(y_pred, y_true, P, samples, accum);
    finalize_kernel<<<1, 64, 0, stream>>>(accum, (float*)d_out, 1.0f / (float)B);
}

// Round 6
// 291.743 us; speedup vs baseline: 2.0589x; 1.4609x over previous
//
#include <hip/hip_runtime.h>
#include <math.h>

#define EPSF 1e-9f
#define KK 128
#define MTOP 10   // m

// One 256-thread block (4 waves) per batch element b.
// Wave w owns sample rows r0=5w..5w+4 (4x5 = 20 rows).
// Lane (0..63) owns columns {2*lane, 2*lane+1}: the wave covers all 128
// computed columns; the identity half lives in the same lanes' vs[] slices.
//
// LESSONS (R1-R5):
//  * Register arrays: compile-time-constant indices ONLY (R2: runtime acc[i]
//    -> whole array in scratch, 41 MB spill traffic).
//  * NEVER pass register arrays by reference to helpers (R4: array-ref params
//    blocked SROA -> 983 MB spill traffic).
//  * NO loop-carried double-buffer arrays in rolled loops (R5: cb[8]/nb[8]
//    with conditional refill stayed in scratch -> 395 MB writes, occupancy
//    capped at 43% by private-segment allocation).
//  * R3-style "load into scalars, consume immediately" verifiably produces
//    zero scratch. Latency hiding comes from TLP: 2048 blocks x 4 waves =
//    8 waves/SIMD at ~45 VGPRs.
__global__ __launch_bounds__(256, 4) void fused_kernel(
    const float* __restrict__ y_pred, const float* __restrict__ y_true,
    const float* __restrict__ P, const float* __restrict__ samples,
    float* __restrict__ accum /* [0]=logmse_sum, [1]=penalty_sum */)
{
    const int tid  = threadIdx.x;
    const int wave = tid >> 6;
    const int lane = tid & 63;
    const int b    = blockIdx.x;
    const int r0   = wave * 5;
    const int j2   = lane << 1;

    const float* __restrict__ Pb = P + ((size_t)b << 14);            // b*128*128
    const float* __restrict__ Sb = samples + (size_t)b * (20 * KK);  // b*20*128

    // vs[r] = S[r0+r][j2..j2+1]; lane m holds elements {2m, 2m+1} of the row.
    // (a) shuffle source for GEMM scalars, (b) identity part for top-k.
    float2 vs[5];
#pragma unroll
    for (int r = 0; r < 5; ++r)
        vs[r] = *(const float2*)(Sb + (r0 + r) * KK + j2);

    float2 acc[5];
#pragma unroll
    for (int r = 0; r < 5; ++r) acc[r] = make_float2(0.f, 0.f);

    // ---- GEMM: acc[r].{x,y} = sum_k S[r0+r][k] * P[k][{j2,j2+1}] ----
    // Two P rows per iteration, loaded into scalars and consumed immediately.
    // S[r][k] = (k even ? vs.x : vs.y) broadcast from lane k/2.
#pragma unroll 2
    for (int k = 0; k < KK; k += 2) {
        float2 p0 = *(const float2*)(Pb + (size_t)k * KK + j2);
        float2 p1 = *(const float2*)(Pb + (size_t)(k + 1) * KK + j2);
        const int sl = k >> 1;
#pragma unroll
        for (int r = 0; r < 5; ++r) {
            float sx = __shfl(vs[r].x, sl, 64);
            float sy = __shfl(vs[r].y, sl, 64);
            acc[r].x = fmaf(sx, p0.x, acc[r].x);
            acc[r].y = fmaf(sx, p0.y, acc[r].y);
            acc[r].x = fmaf(sy, p1.x, acc[r].x);
            acc[r].y = fmaf(sy, p1.y, acc[r].y);
        }
    }

    // ---- Top-11 per row across the wave: 64 lanes x 4 vals = 256 ----
    float hmax = 0.f;
#pragma unroll   // constant indices into acc/vs
    for (int r = 0; r < 5; ++r) {
        float v0 = fabsf(acc[r].x), v1 = fabsf(acc[r].y);
        float v2 = fabsf(vs[r].x),  v3 = fabsf(vs[r].y);
        float m1 = 0.f, m11 = 0.f;
#pragma unroll 1
        for (int it = 0; it <= MTOP; ++it) {
            float lm = fmaxf(fmaxf(v0, v1), fmaxf(v2, v3));
            float Mx = lm;
#pragma unroll
            for (int d = 32; d >= 1; d >>= 1)
                Mx = fmaxf(Mx, __shfl_xor(Mx, d, 64));
            if (it == 0) m1 = Mx;
            if (it == MTOP) { m11 = Mx; break; }
            // remove exactly one instance of Mx (first lane holding it)
            unsigned long long ball = __ballot(lm == Mx);
            int first = __ffsll(ball) - 1;
            if (lane == first) {
                if (v0 == Mx)      v0 = -1.f;
                else if (v1 == Mx) v1 = -1.f;
                else if (v2 == Mx) v2 = -1.f;
                else               v3 = -1.f;
            }
        }
        hmax = fmaxf(hmax, m1 / (m11 + EPSF));   // wave-uniform
    }

    // ---- combine 4 waves, one atomic pair per block ----
    __shared__ float red[4];
    if (lane == 0) red[wave] = hmax;
    __syncthreads();
    if (tid == 0) {
        float hb  = fmaxf(fmaxf(red[0], red[1]), fmaxf(red[2], red[3]));
        float ypv = y_pred[b];
        float yp  = fmaxf(ypv, EPSF);
        float yt  = fmaxf(y_true[b], EPSF);
        float d   = log2f(yt) - log2f(yp);
        atomicAdd(&accum[0], d * d);
        atomicAdd(&accum[1], fmaxf(hb - ypv, 0.f));
    }
}

__global__ void finalize_kernel(const float* __restrict__ accum,
                                float* __restrict__ out, float invB)
{
    if (threadIdx.x == 0) {
        float logmse    = accum[0] * invB;
        float violation = accum[1] * invB;
        out[0] = logmse + 0.5f * violation;
        out[1] = logmse;
        out[2] = violation;
    }
}

extern "C" void kernel_launch(void* const* d_in, const int* in_sizes, int n_in,
                              void* d_out, int out_size, void* d_ws, size_t ws_size,
                              hipStream_t stream) {
    const float* y_pred  = (const float*)d_in[0];
    const float* y_true  = (const float*)d_in[1];
    const float* P       = (const float*)d_in[2];
    const float* samples = (const float*)d_in[3];
    const int B = in_sizes[0];           // y_pred has B elements

    float* accum = (float*)d_ws;
    hipMemsetAsync(accum, 0, 2 * sizeof(float), stream);

    fused_kernel<<<B, 256, 0, stream>>>(y_pred, y_true, P, samples, accum);
    finalize_kernel<<<1, 64, 0, stream>>>(accum, (float*)d_out, 1.0f / (float)B);
}

// Round 7
// 261.814 us; speedup vs baseline: 2.2942x; 1.1143x over previous
//
#include <hip/hip_runtime.h>
#include <math.h>

#define EPSF 1e-9f
#define KK 128
#define MTOP 10   // m

// One 256-thread block (4 waves) per batch element b.
// Wave w owns sample rows r0=5w..5w+4 (4x5 = 20 rows).
// Lane (0..63) owns columns {2*lane, 2*lane+1}: the wave covers all 128
// computed columns; the identity half lives in the same lanes' vs[] slices.
//
// LESSONS (R1-R6):
//  * Register arrays: compile-time-constant indices ONLY, and unconditional
//    writes only (R2: runtime acc[i] -> scratch; R5: conditionally-refilled
//    cb[]/nb[] -> scratch, 395 MB). R6's unconditional constant-index acc[]
//    verifiably stays in VGPRs (WRITE_SIZE 128 B).
//  * NEVER pass register arrays by reference to helpers (R4: SROA blocked,
//    983 MB spill traffic).
//  * R6 was LDS-PIPE bound: ~970 ds_bpermute/wave (shfl broadcasts in GEMM +
//    top-k butterflies) ~= 124k cyc/CU of DS serialization at 22% VALUBusy.
//    This version: S broadcast via wave-uniform ds_read_b128 (640 -> 160 DS
//    ops) and top-k via ballot bisection on float bit patterns (330 -> 30 DS
//    ops, zero bpermute, SALU-pipe popcounts).
__global__ __launch_bounds__(256, 4) void fused_kernel(
    const float* __restrict__ y_pred, const float* __restrict__ y_true,
    const float* __restrict__ P, const float* __restrict__ samples,
    float* __restrict__ accum /* [0]=logmse_sum, [1]=penalty_sum */)
{
    const int tid  = threadIdx.x;
    const int wave = tid >> 6;
    const int lane = tid & 63;
    const int b    = blockIdx.x;
    const int r0   = wave * 5;
    const int j2   = lane << 1;

    const float* __restrict__ Pb = P + ((size_t)b << 14);            // b*128*128
    const float* __restrict__ Sb = samples + (size_t)b * (20 * KK);  // b*20*128

    __shared__ float sS[20 * KK];   // signed S rows, broadcast source (10 KB)
    __shared__ float red[4];

    // ---- stage: load own S slices, mirror into LDS ----
    float2 vs[5];
#pragma unroll
    for (int r = 0; r < 5; ++r) {
        vs[r] = *(const float2*)(Sb + (r0 + r) * KK + j2);
        *(float2*)&sS[(r0 + r) * KK + j2] = vs[r];
    }
    __syncthreads();

    float2 acc[5];
#pragma unroll
    for (int r = 0; r < 5; ++r) acc[r] = make_float2(0.f, 0.f);

    // ---- GEMM: acc[r] += S[r0+r][k] * P[k][{j2,j2+1}] ----
    // 4 P rows per iteration loaded into scalars, consumed immediately (the
    // verified no-spill shape). S scalars arrive 4-at-a-time via ONE
    // wave-uniform ds_read_b128 per row (hardware broadcast, no conflicts).
#pragma unroll 2
    for (int k = 0; k < KK; k += 4) {
        float2 p0 = *(const float2*)(Pb + (k + 0) * KK + j2);
        float2 p1 = *(const float2*)(Pb + (k + 1) * KK + j2);
        float2 p2 = *(const float2*)(Pb + (k + 2) * KK + j2);
        float2 p3 = *(const float2*)(Pb + (k + 3) * KK + j2);
#pragma unroll
        for (int r = 0; r < 5; ++r) {
            float4 s = *(const float4*)&sS[(r0 + r) * KK + k];  // uniform addr
            acc[r].x = fmaf(s.x, p0.x, acc[r].x);
            acc[r].y = fmaf(s.x, p0.y, acc[r].y);
            acc[r].x = fmaf(s.y, p1.x, acc[r].x);
            acc[r].y = fmaf(s.y, p1.y, acc[r].y);
            acc[r].x = fmaf(s.z, p2.x, acc[r].x);
            acc[r].y = fmaf(s.z, p2.y, acc[r].y);
            acc[r].x = fmaf(s.w, p3.x, acc[r].x);
            acc[r].y = fmaf(s.w, p3.y, acc[r].y);
        }
    }

    // ---- top-1 / top-11 per row over 256 wave-distributed values ----
    // m1: 6-shfl max butterfly. m11: binary search on the uint bit pattern
    // (monotone for non-negative floats); returns the EXACT 11th-largest
    // element value as_float(lo+1). Zero DS ops in the search: 4 v_cmp
    // (VALU) + 4 s_bcnt1 (SALU) per iteration, ~31 iterations.
    float hmax = 0.f;
#pragma unroll
    for (int r = 0; r < 5; ++r) {
        float v0 = fabsf(acc[r].x), v1 = fabsf(acc[r].y);
        float v2 = fabsf(vs[r].x),  v3 = fabsf(vs[r].y);
        float m1 = fmaxf(fmaxf(v0, v1), fmaxf(v2, v3));
#pragma unroll
        for (int d = 32; d >= 1; d >>= 1)
            m1 = fmaxf(m1, __shfl_xor(m1, d, 64));
        // invariant: count(> as_float(lo)) >= 11, boundary in [lo, hi]
        unsigned lo = 0u, hi = __float_as_uint(m1);
        while (lo < hi) {
            unsigned mid = lo + ((hi - lo + 1) >> 1);
            float mf = __uint_as_float(mid);
            int cnt = __popcll(__ballot(v0 > mf)) + __popcll(__ballot(v1 > mf))
                    + __popcll(__ballot(v2 > mf)) + __popcll(__ballot(v3 > mf));
            if (cnt >= MTOP + 1) lo = mid; else hi = mid - 1;
        }
        float m11 = __uint_as_float(lo + 1u);   // exact 11th-largest
        hmax = fmaxf(hmax, m1 / (m11 + EPSF));  // wave-uniform
    }

    // ---- combine 4 waves, one atomic pair per block ----
    if (lane == 0) red[wave] = hmax;
    __syncthreads();
    if (tid == 0) {
        float hb  = fmaxf(fmaxf(red[0], red[1]), fmaxf(red[2], red[3]));
        float ypv = y_pred[b];
        float yp  = fmaxf(ypv, EPSF);
        float yt  = fmaxf(y_true[b], EPSF);
        float d   = log2f(yt) - log2f(yp);
        atomicAdd(&accum[0], d * d);
        atomicAdd(&accum[1], fmaxf(hb - ypv, 0.f));
    }
}

__global__ void finalize_kernel(const float* __restrict__ accum,
                                float* __restrict__ out, float invB)
{
    if (threadIdx.x == 0) {
        float logmse    = accum[0] * invB;
        float violation = accum[1] * invB;
        out[0] = logmse + 0.5f * violation;
        out[1] = logmse;
        out[2] = violation;
    }
}

extern "C" void kernel_launch(void* const* d_in, const int* in_sizes, int n_in,
                              void* d_out, int out_size, void* d_ws, size_t ws_size,
                              hipStream_t stream) {
    const float* y_pred  = (const float*)d_in[0];
    const float* y_true  = (const float*)d_in[1];
    const float* P       = (const float*)d_in[2];
    const float* samples = (const float*)d_in[3];
    const int B = in_sizes[0];           // y_pred has B elements

    float* accum = (float*)d_ws;
    hipMemsetAsync(accum, 0, 2 * sizeof(float), stream);

    fused_kernel<<<B, 256, 0, stream>>>(y_pred, y_true, P, samples, accum);
    finalize_kernel<<<1, 64, 0, stream>>>(accum, (float*)d_out, 1.0f / (float)B);
}

// Round 8
// 235.969 us; speedup vs baseline: 2.5455x; 1.1095x over previous
//
#include <hip/hip_runtime.h>
#include <math.h>

#define EPSF 1e-9f
#define KK 128
#define MTOP 10   // m

// One 256-thread block (4 waves) per batch element b.
// Wave w owns sample rows r0=5w..5w+4 (4 waves x 5 = 20 rows).
// K-SPLIT GEMM: half-wave sg=lane>>5 accumulates k in [64*sg, 64*sg+64);
// lane's column group c=lane&31 covers cols 4c..4c+3 (float4 loads = 16B
// coalescing sweet spot, 64 loads/lane instead of R7's 128x8B). Halves are
// combined with one shfl_xor(32) per float. For top-k, lanes 0-31 carry the
// 128 computed-column magnitudes, lanes 32-63 carry the 128 identity
// magnitudes -> the wave holds all 256 values exactly once.
//
// LESSONS (R1-R7):
//  * Register arrays: compile-time-constant indices, unconditional writes
//    (R2/R5: anything else -> scratch, 41-395 MB spill traffic).
//  * NEVER pass register arrays by reference to helpers (R4: 983 MB spills).
//  * Load-into-scalars-consume-immediately is the verified no-spill shape.
//  * R6: shfl-broadcast GEMM is LDS-pipe-bound -> S via wave-uniform
//    ds_read_b128. R7: sequential per-row bisection = 5x31 serial chain ->
//    this version runs the 5 rows' bisections in LOCKSTEP (5-way ILP on the
//    chain, state in SGPRs, counts on SALU).
//  * R7: 2048 blocks x 2 atomicAdd on 2 addresses serialize -> per-block
//    partials to d_ws, reduced by finalize_kernel.
__global__ __launch_bounds__(256, 4) void fused_kernel(
    const float* __restrict__ y_pred, const float* __restrict__ y_true,
    const float* __restrict__ P, const float* __restrict__ samples,
    float* __restrict__ partial /* [2*B]: per-block {logmse_i, penalty_i} */)
{
    const int tid   = threadIdx.x;
    const int wave  = tid >> 6;
    const int lane  = tid & 63;
    const int b     = blockIdx.x;
    const int r0    = wave * 5;
    const int sg    = lane >> 5;     // k-segment of the half-wave
    const int c     = lane & 31;     // column group
    const int j4    = c << 2;
    const int kbase = sg << 6;       // 0 or 64

    const float* __restrict__ Pb = P + ((size_t)b << 14);            // b*128*128
    const float* __restrict__ Sb = samples + (size_t)b * (20 * KK);  // b*20*128

    __shared__ float sS[20 * KK];   // S rows: GEMM broadcast + identity vals
    __shared__ float red[4];

    // ---- stage S into LDS, block-cooperative, coalesced float2 ----
#pragma unroll
    for (int i = 0; i < 5; ++i) {
        const int idx = (i * 256 + tid) * 2;
        *(float2*)&sS[idx] = *(const float2*)(Sb + idx);
    }
    __syncthreads();

    float4 acc[5];
#pragma unroll
    for (int r = 0; r < 5; ++r) acc[r] = make_float4(0.f, 0.f, 0.f, 0.f);

    // ---- GEMM over this half-wave's 64 k values, float4 P loads ----
    const float* __restrict__ Pw = Pb + (size_t)kbase * KK + j4;
#pragma unroll 2
    for (int kk = 0; kk < 64; kk += 4) {
        float4 p0 = *(const float4*)(Pw + (kk + 0) * KK);
        float4 p1 = *(const float4*)(Pw + (kk + 1) * KK);
        float4 p2 = *(const float4*)(Pw + (kk + 2) * KK);
        float4 p3 = *(const float4*)(Pw + (kk + 3) * KK);
#pragma unroll
        for (int r = 0; r < 5; ++r) {
            float4 s = *(const float4*)&sS[(r0 + r) * KK + kbase + kk];
            acc[r].x = fmaf(s.x, p0.x, acc[r].x);
            acc[r].y = fmaf(s.x, p0.y, acc[r].y);
            acc[r].z = fmaf(s.x, p0.z, acc[r].z);
            acc[r].w = fmaf(s.x, p0.w, acc[r].w);
            acc[r].x = fmaf(s.y, p1.x, acc[r].x);
            acc[r].y = fmaf(s.y, p1.y, acc[r].y);
            acc[r].z = fmaf(s.y, p1.z, acc[r].z);
            acc[r].w = fmaf(s.y, p1.w, acc[r].w);
            acc[r].x = fmaf(s.z, p2.x, acc[r].x);
            acc[r].y = fmaf(s.z, p2.y, acc[r].y);
            acc[r].z = fmaf(s.z, p2.z, acc[r].z);
            acc[r].w = fmaf(s.z, p2.w, acc[r].w);
            acc[r].x = fmaf(s.w, p3.x, acc[r].x);
            acc[r].y = fmaf(s.w, p3.y, acc[r].y);
            acc[r].z = fmaf(s.w, p3.z, acc[r].z);
            acc[r].w = fmaf(s.w, p3.w, acc[r].w);
        }
    }

    // ---- combine k-halves; upper half-wave switches to identity values ----
    // After the xor-add every lane holds the full sum for cols 4c..4c+3.
    // Lanes 32-63 then carry |S[r][4c..4c+3]| instead -> 256 values/row
    // distributed exactly once across the wave (4 per lane).
    float w0[5], w1[5], w2[5], w3[5];
#pragma unroll
    for (int r = 0; r < 5; ++r) {
        float ax = acc[r].x + __shfl_xor(acc[r].x, 32, 64);
        float ay = acc[r].y + __shfl_xor(acc[r].y, 32, 64);
        float az = acc[r].z + __shfl_xor(acc[r].z, 32, 64);
        float aw = acc[r].w + __shfl_xor(acc[r].w, 32, 64);
        float4 idv = *(const float4*)&sS[(r0 + r) * KK + j4];
        w0[r] = fabsf(sg ? idv.x : ax);
        w1[r] = fabsf(sg ? idv.y : ay);
        w2[r] = fabsf(sg ? idv.z : az);
        w3[r] = fabsf(sg ? idv.w : aw);
    }

    // ---- m1 per row: lane max + 6-shfl butterfly (5 chains interleave) ----
    float mx[5];
#pragma unroll
    for (int r = 0; r < 5; ++r) {
        float lm = fmaxf(fmaxf(w0[r], w1[r]), fmaxf(w2[r], w3[r]));
#pragma unroll
        for (int d = 32; d >= 1; d >>= 1)
            lm = fmaxf(lm, __shfl_xor(lm, d, 64));
        mx[r] = lm;
    }

    // ---- m11 per row: LOCKSTEP ballot bisection on float bit patterns ----
    // Invariant per row: pattern(m11) in [lo+1, hi+1]; converged rows take
    // the lo=mid branch forever (stable no-op), so lockstep is safe.
    unsigned lo[5], hi[5];
#pragma unroll
    for (int r = 0; r < 5; ++r) { lo[r] = 0u; hi[r] = __float_as_uint(mx[r]); }

    while (lo[0] < hi[0] || lo[1] < hi[1] || lo[2] < hi[2] ||
           lo[3] < hi[3] || lo[4] < hi[4]) {
#pragma unroll
        for (int r = 0; r < 5; ++r) {
            unsigned mid = lo[r] + ((hi[r] - lo[r] + 1u) >> 1);
            float mf = __uint_as_float(mid);
            int cnt = __popcll(__ballot(w0[r] > mf)) + __popcll(__ballot(w1[r] > mf))
                    + __popcll(__ballot(w2[r] > mf)) + __popcll(__ballot(w3[r] > mf));
            bool g = cnt >= (MTOP + 1);
            lo[r] = g ? mid : lo[r];
            hi[r] = g ? hi[r] : mid - 1u;
        }
    }

    float hmax = 0.f;
#pragma unroll
    for (int r = 0; r < 5; ++r) {
        float m11 = __uint_as_float(lo[r] + 1u);   // exact 11th-largest
        hmax = fmaxf(hmax, mx[r] / (m11 + EPSF));  // wave-uniform
    }

    // ---- combine 4 waves; per-block partials (no atomics) ----
    if (lane == 0) red[wave] = hmax;
    __syncthreads();
    if (tid == 0) {
        float hb  = fmaxf(fmaxf(red[0], red[1]), fmaxf(red[2], red[3]));
        float ypv = y_pred[b];
        float yp  = fmaxf(ypv, EPSF);
        float yt  = fmaxf(y_true[b], EPSF);
        float d   = log2f(yt) - log2f(yp);
        partial[2 * b]     = d * d;
        partial[2 * b + 1] = fmaxf(hb - ypv, 0.f);
    }
}

__global__ __launch_bounds__(256) void finalize_kernel(
    const float* __restrict__ partial, float* __restrict__ out, float invB)
{
    const int t = threadIdx.x;
    float sl = 0.f, sp = 0.f;
#pragma unroll
    for (int i = 0; i < 8; ++i) {
        float2 v = *(const float2*)(partial + 2 * (t + i * 256));
        sl += v.x; sp += v.y;
    }
#pragma unroll
    for (int d = 32; d >= 1; d >>= 1) {
        sl += __shfl_xor(sl, d, 64);
        sp += __shfl_xor(sp, d, 64);
    }
    __shared__ float rl[4], rp[4];
    const int w = t >> 6;
    if ((t & 63) == 0) { rl[w] = sl; rp[w] = sp; }
    __syncthreads();
    if (t == 0) {
        float L = (rl[0] + rl[1] + rl[2] + rl[3]) * invB;
        float V = (rp[0] + rp[1] + rp[2] + rp[3]) * invB;
        out[0] = L + 0.5f * V;
        out[1] = L;
        out[2] = V;
    }
}

extern "C" void kernel_launch(void* const* d_in, const int* in_sizes, int n_in,
                              void* d_out, int out_size, void* d_ws, size_t ws_size,
                              hipStream_t stream) {
    const float* y_pred  = (const float*)d_in[0];
    const float* y_true  = (const float*)d_in[1];
    const float* P       = (const float*)d_in[2];
    const float* samples = (const float*)d_in[3];
    const int B = in_sizes[0];           // y_pred has B elements

    float* partial = (float*)d_ws;       // 2*B floats, fully overwritten

    fused_kernel<<<B, 256, 0, stream>>>(y_pred, y_true, P, samples, partial);
    finalize_kernel<<<1, 256, 0, stream>>>(partial, (float*)d_out, 1.0f / (float)B);
}